// Round 1
// 388.020 us; speedup vs baseline: 1.1050x; 1.1050x over previous
//
#include <hip/hip_runtime.h>
#include <hip/hip_bf16.h>
#include <stdint.h>

#define D_IN  4096
#define D_OUT 4096
#define MROWS 8192   // 2 * 4096 rows of x

using i32x4 = __attribute__((ext_vector_type(4))) int;

// -------- Kernel 1 (fused): RMSNorm -> i8 xn (per-row absmax scale)
//          AND w_q fp32 -> i8 (exact, values in {-1,0,1}) ------------------
// Blocks [0, MROWS): one block per row of x.
// Blocks [MROWS, MROWS+4096): convert w_q, 16 floats per thread, coalesced.
__global__ __launch_bounds__(256) void prep_kernel(
    const float* __restrict__ x, const float* __restrict__ nw,
    signed char* __restrict__ xq, float* __restrict__ srow,
    const float* __restrict__ wq, signed char* __restrict__ wb) {
  const int b = blockIdx.x;
  const int t = threadIdx.x;

  if (b < MROWS) {
    const float4* xr  = (const float4*)(x + (size_t)b * D_IN);
    const float4* nw4 = (const float4*)nw;

    float4 p[4];
    float ss = 0.f, mx = 0.f;
#pragma unroll
    for (int i = 0; i < 4; ++i) {
      const float4 v = xr[i * 256 + t];
      const float4 w = nw4[i * 256 + t];
      ss += v.x * v.x + v.y * v.y + v.z * v.z + v.w * v.w;
      p[i].x = v.x * w.x; p[i].y = v.y * w.y;
      p[i].z = v.z * w.z; p[i].w = v.w * w.w;
      mx = fmaxf(mx, fmaxf(fmaxf(fabsf(p[i].x), fabsf(p[i].y)),
                           fmaxf(fabsf(p[i].z), fabsf(p[i].w))));
    }
#pragma unroll
    for (int off = 32; off > 0; off >>= 1) {
      ss += __shfl_down(ss, off, 64);
      mx = fmaxf(mx, __shfl_down(mx, off, 64));
    }

    __shared__ float rs[4], rm[4];
    if ((t & 63) == 0) { rs[t >> 6] = ss; rm[t >> 6] = mx; }
    __syncthreads();
    const float scale =
        rsqrtf((rs[0] + rs[1] + rs[2] + rs[3]) * (1.0f / D_IN) + 1e-6f);
    const float rowmax = fmaxf(fmaxf(rm[0], rm[1]), fmaxf(rm[2], rm[3])) * scale;
    const float s   = fmaxf(rowmax, 1e-20f) * (1.0f / 127.0f);
    const float f   = scale / s;   // = scale * 127 / rowmax
    if (t == 0) srow[b] = s;

    int* out = (int*)(xq + (size_t)b * D_IN);
#pragma unroll
    for (int i = 0; i < 4; ++i) {
      const int q0 = (int)rintf(p[i].x * f);
      const int q1 = (int)rintf(p[i].y * f);
      const int q2 = (int)rintf(p[i].z * f);
      const int q3 = (int)rintf(p[i].w * f);
      out[i * 256 + t] =
          (q0 & 0xFF) | ((q1 & 0xFF) << 8) | ((q2 & 0xFF) << 16) | (q3 << 24);
    }
  } else {
    // ---- w_q conversion, fully coalesced: float4 idx cb*1024 + i*256 + t --
    const int cb = b - MROWS;
    const float4* w4 = (const float4*)wq;
    int* o = (int*)wb;
#pragma unroll
    for (int i = 0; i < 4; ++i) {
      const int idx = cb * 1024 + i * 256 + t;
      const float4 v = w4[idx];
      const int q0 = (int)v.x, q1 = (int)v.y, q2 = (int)v.z, q3 = (int)v.w;
      o[idx] = (q0 & 0xFF) | ((q1 & 0xFF) << 8) | ((q2 & 0xFF) << 16) | (q3 << 24);
    }
  }
}

// ---------------- Kernel 2: i8 GEMM (A: MxK, B: NxK i.e. B^T) -------------
// mfma_i32_16x16x64_i8: per lane A[m=lane&15][k=(lane>>4)*16 + j], j in [0,16).
// C/D layout (shape-determined): col=lane&15, row=(lane>>4)*4+reg.
// LDS XOR-swizzle (proven 0 conflicts): 16B chunk (row, j) lives at slot
// j ^ ((row>>1)&3); applied by permuting the *global source* chunk
// (global_load_lds forces LDS slot = lane order), compensated in ds_read.
//
// NEW STRUCTURE (this round): 256x256 tile, 512 threads (8 waves, 2Mx4N),
// 4-deep LDS ring (4 x 16KB per operand = 128 KB total, 1 block/CU).
// Counted s_waitcnt vmcnt(8) + raw s_barrier per K-step — loads for tiles
// t+1..t+3 stay in flight across barriers (never drain to vmcnt(0) in the
// main loop). s_setprio(1) wraps the 32-MFMA cluster.
#define BM 256
#define BN 256
#define BKB 64                  // K bytes per tile == one MFMA k-step
#define NKT (D_IN / BKB)        // 64 K-tiles
#define SLOT_BYTES (BM * BKB)   // 16 KB per ring slot per operand

#define WVM(n_) asm volatile("s_waitcnt vmcnt(" #n_ ")" ::: "memory")
#define BAR()   __builtin_amdgcn_s_barrier()

#define STAGE(t_, s_)                                                         \
  do {                                                                        \
    const int _k0 = (t_) * BKB;                                               \
    _Pragma("unroll") for (int _i = 0; _i < 2; ++_i)                          \
        __builtin_amdgcn_global_load_lds(                                     \
            (__attribute__((address_space(1))) void*)(A + aOff[_i] + _k0),    \
            (__attribute__((address_space(3))) void*)&sA[s_][ldsOff[_i]],     \
            16, 0, 0);                                                        \
    _Pragma("unroll") for (int _i = 0; _i < 2; ++_i)                          \
        __builtin_amdgcn_global_load_lds(                                     \
            (__attribute__((address_space(1))) void*)(B + bOff[_i] + _k0),    \
            (__attribute__((address_space(3))) void*)&sB[s_][ldsOff[_i]],     \
            16, 0, 0);                                                        \
  } while (0)

#define COMPUTE(s_)                                                           \
  do {                                                                        \
    i32x4 af[8], bfr[4];                                                      \
    _Pragma("unroll") for (int _i = 0; _i < 8; ++_i)                          \
        af[_i] = *(const i32x4*)&sA[s_][aoff + _i * (16 * BKB)];              \
    _Pragma("unroll") for (int _j = 0; _j < 4; ++_j)                          \
        bfr[_j] = *(const i32x4*)&sB[s_][boff + _j * (16 * BKB)];             \
    __builtin_amdgcn_s_setprio(1);                                            \
    _Pragma("unroll") for (int _i = 0; _i < 8; ++_i)                          \
        _Pragma("unroll") for (int _j = 0; _j < 4; ++_j)                      \
            acc[_i][_j] = __builtin_amdgcn_mfma_i32_16x16x64_i8(              \
                af[_i], bfr[_j], acc[_i][_j], 0, 0, 0);                       \
    __builtin_amdgcn_s_setprio(0);                                            \
  } while (0)

__global__ __launch_bounds__(512, 2) void gemm_kernel(
    const signed char* __restrict__ A,   // MROWS x D_IN i8
    const signed char* __restrict__ B,   // D_OUT x D_IN i8
    const float* __restrict__ srow,      // MROWS   (per-row dequant scale)
    const float* __restrict__ gamma,     // D_OUT
    float* __restrict__ C) {             // MROWS x D_OUT fp32
  __shared__ __align__(16) signed char sA[4][SLOT_BYTES];  // 64 KB
  __shared__ __align__(16) signed char sB[4][SLOT_BYTES];  // 64 KB

  const int tid  = threadIdx.x;
  const int lane = tid & 63;
  const int wv   = tid >> 6;     // 0..7
  const int wm   = wv >> 2;      // 0..1: 128-row half of the 256-row tile
  const int wn   = wv & 3;       // 0..3: 64-col quarter of the 256-col tile
  const int bn   = blockIdx.x;   // 0..15
  const int bm   = blockIdx.y;   // 0..31

  i32x4 acc[8][4];
#pragma unroll
  for (int i = 0; i < 8; ++i)
#pragma unroll
    for (int j = 0; j < 4; ++j) acc[i][j] = (i32x4){0, 0, 0, 0};

  // Staging map: per tile per operand 1024 chunks of 16B; chunk
  // c = i*512 + tid -> tile row r = c>>2, swizzled k-byte offset.
  size_t aOff[2], bOff[2];
  int ldsOff[2];
#pragma unroll
  for (int i = 0; i < 2; ++i) {
    const int c  = i * 512 + tid;
    const int r  = c >> 2;
    const int cc = ((c & 3) ^ ((r >> 1) & 3)) * 16;
    aOff[i] = (size_t)(bm * BM + r) * D_IN + cc;
    bOff[i] = (size_t)(bn * BN + r) * D_IN + cc;
    ldsOff[i] = (i * 512 + wv * 64) * 16;  // wave-uniform base; +lane*16 by HW
  }

  // Fragment read offsets (swizzle-compensated; row base is a multiple of
  // 16 so (row>>1)&3 == (lane>>1)&3).
  const int kk   = (((lane >> 4) ^ ((lane >> 1) & 3))) * 16;
  const int aoff = (wm * 128 + (lane & 15)) * BKB + kk;
  const int boff = (wn * 64  + (lane & 15)) * BKB + kk;

  // Prologue: fill 3 ring slots, wait for tile 0 (8 loads may stay in flight)
  STAGE(0, 0);
  STAGE(1, 1);
  STAGE(2, 2);
  WVM(8);
  BAR();

  // Main loop: compute tile t (slot t&3), stage tile t+3, then wait for
  // tile t+1 (vmcnt(8): tiles t+2, t+3 remain outstanding) + barrier.
#pragma unroll 1
  for (int t4 = 0; t4 < NKT - 4; t4 += 4) {
    STAGE(t4 + 3, 3); COMPUTE(0); WVM(8); BAR();
    STAGE(t4 + 4, 0); COMPUTE(1); WVM(8); BAR();
    STAGE(t4 + 5, 1); COMPUTE(2); WVM(8); BAR();
    STAGE(t4 + 6, 2); COMPUTE(3); WVM(8); BAR();
  }
  // Tail: tiles 60..63
  STAGE(NKT - 1, 3); COMPUTE(0); WVM(8); BAR();
  COMPUTE(1); WVM(4); BAR();
  COMPUTE(2); WVM(0); BAR();
  COMPUTE(3);

  // Epilogue: y = acc * srow[row] * gamma[col]
  const int col0 = bn * BN + wn * 64 + (lane & 15);
  const int row0 = bm * BM + wm * 128 + ((lane >> 4) * 4);
  float g[4];
#pragma unroll
  for (int j = 0; j < 4; ++j) g[j] = gamma[col0 + j * 16];

#pragma unroll
  for (int i = 0; i < 8; ++i) {
#pragma unroll
    for (int r = 0; r < 4; ++r) {
      const int row = row0 + i * 16 + r;
      const float sr = srow[row];
#pragma unroll
      for (int j = 0; j < 4; ++j) {
        C[(size_t)row * D_OUT + col0 + j * 16] =
            (float)acc[i][j][r] * sr * g[j];
      }
    }
  }
}

#undef STAGE
#undef COMPUTE
#undef WVM
#undef BAR

extern "C" void kernel_launch(void* const* d_in, const int* in_sizes, int n_in,
                              void* d_out, int out_size, void* d_ws, size_t ws_size,
                              hipStream_t stream) {
  const float* x     = (const float*)d_in[0];  // (2,4096,4096)
  const float* nw    = (const float*)d_in[1];  // (4096,)
  const float* wq    = (const float*)d_in[2];  // (4096,4096) {-1,0,1}
  const float* gamma = (const float*)d_in[3];  // (4096,)
  float* y = (float*)d_out;

  // Workspace: xq i8 (32 MB) | wb i8 (16 MB) | srow fp32 (32 KB)
  signed char* xq = (signed char*)d_ws;
  signed char* wb = xq + (size_t)MROWS * D_IN;
  float* srow = (float*)(wb + (size_t)D_OUT * D_IN);

  // 8192 rmsnorm blocks + 4096 cvt blocks in one dispatch
  prep_kernel<<<MROWS + 4096, 256, 0, stream>>>(x, nw, xq, srow, wq, wb);

  gemm_kernel<<<dim3(D_OUT / BN, MROWS / BM), 512, 0, stream>>>(xq, wb, srow, gamma, y);
}